// Round 2
// baseline (368.326 us; speedup 1.0000x reference)
//
#include <hip/hip_runtime.h>

// Problem constants
#define B_SZ   64
#define IC_N   128
#define OC_N   128
#define OUT_D  1024
#define L_N    2048

typedef __attribute__((ext_vector_type(8))) __bf16          bf16x8;
typedef __attribute__((ext_vector_type(8))) unsigned short  u16x8;
typedef __attribute__((ext_vector_type(4))) float           f32x4;

// RNE fp32->bf16, packed pair (lo in low 16 bits).
__device__ __forceinline__ unsigned pack2bf(float lo, float hi) {
    unsigned ul = __builtin_bit_cast(unsigned, lo);
    unsigned uh = __builtin_bit_cast(unsigned, hi);
    ul += 0x7fffu + ((ul >> 16) & 1u);
    uh += 0x7fffu + ((uh >> 16) & 1u);
    return (ul >> 16) | (uh & 0xffff0000u);
}

// ============================= PASS 1: repack ===============================
// xf[d][ch][mt][lane(quad,col)][j] = bf16 x[b=16mt+col][ic=16ch+4q+(j>>1)][l=2d+(j&1)]
//   slot (16B units) = ((d*8+ch)*4+mt)*64 + lane                (33.55 MB)
// wf[ocb][d][ch][nt][lane][j]      = bf16 w[oc=32ocb+16nt+col][ic=16ch+4q+(j>>1)][l=2d+(j&1)]
//   slot = (((ocb*1024+d)*8+ch)*2+nt)*64 + lane                 (67.11 MB)
//
// Block tile: 256 rows (16 "row-group" x 16 ic) x 256 floats of l (1 KB/row
// contiguous reads), processed in 4 windows of 64 floats via a 33 KB LDS
// transpose. x blocks: rg=mt(4) x ch(8) x dg(8) = 256; w blocks: rg=og(8,
// og=2*ocb+nt) x ch(8) x dg(8) = 512. Total grid 768.
__global__ __launch_bounds__(256, 4)
void repack_kernel(const float* __restrict__ x, const float* __restrict__ w,
                   unsigned short* __restrict__ xf, unsigned short* __restrict__ wf) {
    __shared__ unsigned tile[16 * 16 * 33];  // [ic16][r16][32dw +1 pad] = 33 KB

    const int bid = blockIdx.x;
    const int t    = threadIdx.x;
    const int ic_l = t & 15;
    const int r_l  = t >> 4;
    const int wv   = t >> 6, lane = t & 63;
    const int col  = lane & 15, quad = lane >> 4;

    const bool isw = (bid >= 256);
    int dg, ch, rg;
    if (!isw) { dg = bid & 7;  ch = (bid >> 3) & 7;  rg = bid >> 6; }          // rg = mt
    else      { const int b2 = bid - 256; dg = b2 & 7; ch = (b2 >> 3) & 7; rg = b2 >> 6; } // rg = og

    const float* src = isw ? w : x;
    const float* srow = src + (size_t)((rg * 16 + r_l) * 128 + ch * 16 + ic_l) * L_N + dg * 256;

    for (int p = 0; p < 4; ++p) {
        // ---- read: 16 contiguous float4 per thread (1 KB/row over 4 windows) ----
        float4 v[16];
#pragma unroll
        for (int k = 0; k < 16; ++k)
            v[k] = *(const float4*)&srow[p * 64 + 4 * k];

        __syncthreads();  // previous window's LDS reads done

        // ---- convert + LDS store: tile[ic][r][lpair] ----
#pragma unroll
        for (int k = 0; k < 16; ++k) {
            const int base = (ic_l * 16 + r_l) * 33 + 2 * k;
            tile[base]     = pack2bf(v[k].x, v[k].y);
            tile[base + 1] = pack2bf(v[k].z, v[k].w);
        }

        __syncthreads();

        // ---- gather fragment dwords + coalesced 16B global writes ----
#pragma unroll
        for (int dd = 0; dd < 8; ++dd) {
            const int dl = wv * 8 + dd;                    // 0..31 within window
            unsigned dw0 = tile[((4 * quad + 0) * 16 + col) * 33 + dl];
            unsigned dw1 = tile[((4 * quad + 1) * 16 + col) * 33 + dl];
            unsigned dw2 = tile[((4 * quad + 2) * 16 + col) * 33 + dl];
            unsigned dw3 = tile[((4 * quad + 3) * 16 + col) * 33 + dl];
            const int d = dg * 128 + p * 32 + dl;
            size_t slot;
            unsigned short* dst;
            if (!isw) {
                slot = (((size_t)d * 8 + ch) * 4 + rg) * 64 + lane;
                dst = xf;
            } else {
                slot = ((((size_t)(rg >> 1) * 1024 + d) * 8 + ch) * 2 + (rg & 1)) * 64 + lane;
                dst = wf;
            }
            *(uint4*)&dst[slot * 8] = make_uint4(dw0, dw1, dw2, dw3);
        }
    }
}

// ============================= PASS 2: GEMM =================================
// One wave per (d, ocb): C(64x32) = sum_ch X(64x32k) * W(32x32k)^T, fragments
// loaded straight from global (coalesced 1 KB dwordx4), no LDS, no barriers.
__global__ __launch_bounds__(256, 4)
void gemm_frag_kernel(const unsigned short* __restrict__ xf,
                      const unsigned short* __restrict__ wf,
                      float* __restrict__ out) {
    const int bid = blockIdx.x;          // 1024 blocks
    const int ocb = bid & 3;
    const int dm  = bid >> 2;            // 0..255
    const int t   = threadIdx.x, wv = t >> 6, lane = t & 63;
    const int col = lane & 15, quad = lane >> 4;
    const int d   = dm * 4 + wv;

    const u16x8* xp = (const u16x8*)xf + (size_t)d * 2048 + lane;                    // + ch*256 + mt*64
    const u16x8* wp = (const u16x8*)wf + ((size_t)ocb * 1024 + d) * 1024 + lane;     // + ch*128 + nt*64

    f32x4 acc[4][2];
#pragma unroll
    for (int mt = 0; mt < 4; ++mt)
#pragma unroll
        for (int nt = 0; nt < 2; ++nt)
            acc[mt][nt] = (f32x4){0.f, 0.f, 0.f, 0.f};

#pragma unroll
    for (int ch = 0; ch < 8; ++ch) {
        bf16x8 a[4], b[2];
#pragma unroll
        for (int mt = 0; mt < 4; ++mt)
            a[mt] = __builtin_bit_cast(bf16x8, xp[ch * 256 + mt * 64]);
#pragma unroll
        for (int nt = 0; nt < 2; ++nt)
            b[nt] = __builtin_bit_cast(bf16x8, wp[ch * 128 + nt * 64]);
#pragma unroll
        for (int mt = 0; mt < 4; ++mt)
#pragma unroll
            for (int nt = 0; nt < 2; ++nt)
                acc[mt][nt] = __builtin_amdgcn_mfma_f32_16x16x32_bf16(
                    a[mt], b[nt], acc[mt][nt], 0, 0, 0);
    }

    const float scale = 0.088388347648318447f;  // 1/sqrt(128)
#pragma unroll
    for (int mt = 0; mt < 4; ++mt)
#pragma unroll
        for (int nt = 0; nt < 2; ++nt)
#pragma unroll
            for (int r = 0; r < 4; ++r) {
                const int b = 16 * mt + 4 * quad + r;
                const int o = 32 * ocb + 16 * nt + col;
                out[(size_t)(b * OC_N + o) * OUT_D + d] = acc[mt][nt][r] * scale;
            }
}

// ===================== fallback (round-1 kernel, passing) ====================
#define D_TILE 8
#define N_TILE 32
#define KC     16
#define KPAD   40

__global__ __launch_bounds__(256, 2)
void lc1d_fallback(const float* __restrict__ x, const float* __restrict__ w,
                   float* __restrict__ out) {
    __shared__ __align__(16) unsigned short Xs[D_TILE][B_SZ][KPAD];
    __shared__ __align__(16) unsigned short Ws[D_TILE][N_TILE][KPAD];

    const int t     = threadIdx.x;
    const int wv_id = t >> 6;
    const int lane  = t & 63;
    const int col   = lane & 15;
    const int quad  = lane >> 4;

    const int oc_blk = blockIdx.x & 3;
    const int dg     = blockIdx.x >> 2;
    const int o0     = oc_blk * N_TILE;
    const int l0     = dg * (2 * D_TILE);

    f32x4 acc[2][4][2];
#pragma unroll
    for (int dl = 0; dl < 2; ++dl)
#pragma unroll
        for (int mt = 0; mt < 4; ++mt)
#pragma unroll
            for (int nt = 0; nt < 2; ++nt)
                acc[dl][mt][nt] = (f32x4){0.f, 0.f, 0.f, 0.f};

    for (int chunk = 0; chunk < IC_N / KC; ++chunk) {
        const int i0 = chunk * KC;
        float4 xv[16];
#pragma unroll
        for (int r = 0; r < 16; ++r) {
            const int f = t + 256 * r, b = f >> 6, il = (f >> 2) & 15, j = f & 3;
            xv[r] = *(const float4*)&x[(size_t)(b * IC_N + i0 + il) * L_N + l0 + 4 * j];
        }
        float4 wvv[8];
#pragma unroll
        for (int r = 0; r < 8; ++r) {
            const int f = t + 256 * r, ol = f >> 6, il = (f >> 2) & 15, j = f & 3;
            wvv[r] = *(const float4*)&w[(size_t)((o0 + ol) * IC_N + i0 + il) * L_N + l0 + 4 * j];
        }
        __syncthreads();
#pragma unroll
        for (int r = 0; r < 16; ++r) {
            const int f = t + 256 * r, b = f >> 6, il = (f >> 2) & 15, j = f & 3;
            *(unsigned*)&Xs[2 * j][b][2 * il]     = pack2bf(xv[r].x, xv[r].y);
            *(unsigned*)&Xs[2 * j + 1][b][2 * il] = pack2bf(xv[r].z, xv[r].w);
        }
#pragma unroll
        for (int r = 0; r < 8; ++r) {
            const int f = t + 256 * r, ol = f >> 6, il = (f >> 2) & 15, j = f & 3;
            *(unsigned*)&Ws[2 * j][ol][2 * il]     = pack2bf(wvv[r].x, wvv[r].y);
            *(unsigned*)&Ws[2 * j + 1][ol][2 * il] = pack2bf(wvv[r].z, wvv[r].w);
        }
        __syncthreads();
#pragma unroll
        for (int dl = 0; dl < 2; ++dl) {
            const int dp = 2 * wv_id + dl;
            bf16x8 afr[4];
            bf16x8 bfr[2];
#pragma unroll
            for (int mt = 0; mt < 4; ++mt)
                afr[mt] = __builtin_bit_cast(bf16x8, *(const u16x8*)&Xs[dp][16 * mt + col][quad * 8]);
#pragma unroll
            for (int nt = 0; nt < 2; ++nt)
                bfr[nt] = __builtin_bit_cast(bf16x8, *(const u16x8*)&Ws[dp][16 * nt + col][quad * 8]);
#pragma unroll
            for (int mt = 0; mt < 4; ++mt)
#pragma unroll
                for (int nt = 0; nt < 2; ++nt)
                    acc[dl][mt][nt] = __builtin_amdgcn_mfma_f32_16x16x32_bf16(
                        afr[mt], bfr[nt], acc[dl][mt][nt], 0, 0, 0);
        }
    }

    const float scale = 0.088388347648318447f;
    const int dbase = dg * D_TILE + 2 * wv_id;
#pragma unroll
    for (int mt = 0; mt < 4; ++mt)
#pragma unroll
        for (int nt = 0; nt < 2; ++nt)
#pragma unroll
            for (int reg = 0; reg < 4; ++reg) {
                const int b = 16 * mt + 4 * quad + reg;
                const int o = o0 + 16 * nt + col;
                float2 v2;
                v2.x = acc[0][mt][nt][reg] * scale;
                v2.y = acc[1][mt][nt][reg] * scale;
                *(float2*)&out[(size_t)(b * OC_N + o) * OUT_D + dbase] = v2;
            }
}

// ================================ launch ====================================
extern "C" void kernel_launch(void* const* d_in, const int* in_sizes, int n_in,
                              void* d_out, int out_size, void* d_ws, size_t ws_size,
                              hipStream_t stream) {
    const float* x = (const float*)d_in[0];
    const float* w = (const float*)d_in[1];
    float* out     = (float*)d_out;

    const size_t XF_BYTES = (size_t)B_SZ * IC_N * L_N * 2;   // 33,554,432
    const size_t WF_BYTES = (size_t)OC_N * IC_N * L_N * 2;   // 67,108,864

    if (ws_size >= XF_BYTES + WF_BYTES) {
        unsigned short* xf = (unsigned short*)d_ws;
        unsigned short* wfp = (unsigned short*)((char*)d_ws + XF_BYTES);
        hipLaunchKernelGGL(repack_kernel, dim3(768), dim3(256), 0, stream, x, w, xf, wfp);
        hipLaunchKernelGGL(gemm_frag_kernel, dim3(1024), dim3(256), 0, stream, xf, wfp, out);
    } else {
        hipLaunchKernelGGL(lc1d_fallback, dim3(512), dim3(256), 0, stream, x, w, out);
    }
}

// Round 3
// 299.281 us; speedup vs baseline: 1.2307x; 1.2307x over previous
//
#include <hip/hip_runtime.h>

// Problem constants
#define B_SZ   64
#define IC_N   128
#define OC_N   128
#define OUT_D  1024
#define L_N    2048

typedef __attribute__((ext_vector_type(8))) __bf16          bf16x8;
typedef __attribute__((ext_vector_type(8))) unsigned short  u16x8;
typedef __attribute__((ext_vector_type(4))) float           f32x4;

// RNE fp32->bf16, packed pair (lo in low 16 bits).
__device__ __forceinline__ unsigned pack2bf(float lo, float hi) {
    unsigned ul = __builtin_bit_cast(unsigned, lo);
    unsigned uh = __builtin_bit_cast(unsigned, hi);
    ul += 0x7fffu + ((ul >> 16) & 1u);
    uh += 0x7fffu + ((uh >> 16) & 1u);
    return (ul >> 16) | (uh & 0xffff0000u);
}

// ============================= PASS 1: repack ===============================
// Packed layouts (16B units, identical to round 2 — verified correct):
// xf slot = ((d*8+ch)*4+mt)*64 + lane : x[b=16mt+col][ic=16ch+4q+(e>>1)][l=2d+(e&1)]
// wf slot = (((ocb*1024+d)*8+ch)*2+nt)*64 + lane : w[oc=32ocb+16nt+col][...]
//
// LDS relayout vs round 2: tile2[dl 32][row 256(+4 pad)] with row = ic + 16*r.
//  - store: bank = 8k + ic + 16*(r&1) -> 2-way (free)
//  - gather: ONE ds_read_b128 per 16B output unit (rows 4q+0..3 consecutive)
__global__ __launch_bounds__(256, 4)
void repack_kernel(const float* __restrict__ x, const float* __restrict__ w,
                   unsigned short* __restrict__ xf, unsigned short* __restrict__ wf) {
    __shared__ unsigned tile2[32 * 260];  // [dl][row], 33.3 KB

    const int bid = blockIdx.x;
    const int t    = threadIdx.x;
    const int ic_l = t & 15;
    const int r_l  = t >> 4;
    const int wv   = t >> 6, lane = t & 63;
    const int col  = lane & 15, quad = lane >> 4;

    const bool isw = (bid >= 256);
    int dg, ch, rg;
    if (!isw) { dg = bid & 7;  ch = (bid >> 3) & 7;  rg = bid >> 6; }          // rg = mt
    else      { const int b2 = bid - 256; dg = b2 & 7; ch = (b2 >> 3) & 7; rg = b2 >> 6; } // rg = og

    const float* src = isw ? w : x;
    const float* srow = src + (size_t)((rg * 16 + r_l) * 128 + ch * 16 + ic_l) * L_N + dg * 256;
    const int rowbase = ic_l + 16 * r_l;

    for (int p = 0; p < 4; ++p) {
        // ---- read: 16 contiguous float4 per thread (256B burst per window) ----
        float4 v[16];
#pragma unroll
        for (int k = 0; k < 16; ++k)
            v[k] = *(const float4*)&srow[p * 64 + 4 * k];

        __syncthreads();  // previous window's LDS gathers done

        // ---- convert + LDS store: tile2[dl][row], 2-way banks ----
#pragma unroll
        for (int k = 0; k < 16; ++k) {
            tile2[(2 * k) * 260 + rowbase]     = pack2bf(v[k].x, v[k].y);
            tile2[(2 * k + 1) * 260 + rowbase] = pack2bf(v[k].z, v[k].w);
        }

        __syncthreads();

        // ---- gather fragment 16B via single b128 + coalesced global writes ----
#pragma unroll
        for (int dd = 0; dd < 8; ++dd) {
            const int dl = wv * 8 + dd;                    // 0..31 within window
            const uint4 val = *(const uint4*)&tile2[dl * 260 + 16 * col + 4 * quad];
            const int d = dg * 128 + p * 32 + dl;
            size_t slot;
            unsigned short* dst;
            if (!isw) {
                slot = (((size_t)d * 8 + ch) * 4 + rg) * 64 + lane;
                dst = xf;
            } else {
                slot = ((((size_t)(rg >> 1) * 1024 + d) * 8 + ch) * 2 + (rg & 1)) * 64 + lane;
                dst = wf;
            }
            *(uint4*)&dst[slot * 8] = val;
        }
    }
}

// ============================= PASS 2: GEMM =================================
// Block = 8 consecutive d x 64 b x 64 oc (och half). 8 waves; wave = one d,
// C(64x64) = sum_ch X(64x32k) * W(64x32k)^T. xf read 2x, wf 1x (167 MB logical).
// Epilogue: LDS transpose so each lane stores 32B d-runs -> full-line L2 merges
// with the dg-neighbor block (same XCD via swizzle).
__global__ __launch_bounds__(512, 2)
void gemm2_kernel(const unsigned short* __restrict__ xf,
                  const unsigned short* __restrict__ wf,
                  float* __restrict__ out) {
    __shared__ float eplds[16 * 64 * 10 + 8];  // [b16][o64][d8 + 2 pad] = 40 KB

    const int bid = blockIdx.x;
    // XCD swizzle: dg and dg^1 share bid&7 (same XCD) so their 32B half-lines
    // merge in one L2 before eviction.
    const int g   = (bid & 7) * 32 + (bid >> 3);
    const int och = g >> 7;          // 0..1 (oc half)
    const int dg  = g & 127;         // 0..127, 8 d's each
    const int t = threadIdx.x, wv = t >> 6, lane = t & 63;
    const int col = lane & 15, quad = lane >> 4;
    const int d = dg * 8 + wv;

    const u16x8* xp = (const u16x8*)xf + (size_t)d * 2048 + lane;
    const u16x8* wp[4];
#pragma unroll
    for (int ntg = 0; ntg < 4; ++ntg) {
        const size_t ocb = och * 2 + (ntg >> 1);
        const size_t nt  = ntg & 1;
        wp[ntg] = (const u16x8*)wf + (((ocb * 1024 + d) * 8) * 2 + nt) * 64 + lane;
    }

    f32x4 acc[4][4];
#pragma unroll
    for (int mt = 0; mt < 4; ++mt)
#pragma unroll
        for (int ntg = 0; ntg < 4; ++ntg)
            acc[mt][ntg] = (f32x4){0.f, 0.f, 0.f, 0.f};

#pragma unroll
    for (int ch = 0; ch < 8; ++ch) {
        bf16x8 a[4], b[4];
#pragma unroll
        for (int mt = 0; mt < 4; ++mt)
            a[mt] = __builtin_bit_cast(bf16x8, xp[ch * 256 + mt * 64]);
#pragma unroll
        for (int ntg = 0; ntg < 4; ++ntg)
            b[ntg] = __builtin_bit_cast(bf16x8, wp[ntg][ch * 128]);
#pragma unroll
        for (int mt = 0; mt < 4; ++mt)
#pragma unroll
            for (int ntg = 0; ntg < 4; ++ntg)
                acc[mt][ntg] = __builtin_amdgcn_mfma_f32_16x16x32_bf16(
                    a[mt], b[ntg], acc[mt][ntg], 0, 0, 0);
    }

    // ---- epilogue: 4 b-chunks of 16; LDS transpose -> 32B d-run stores ----
    const float scale = 0.088388347648318447f;  // 1/sqrt(128)
    const int o_base = och * 64;
#pragma unroll
    for (int r = 0; r < 4; ++r) {
        __syncthreads();  // previous chunk's reads done
#pragma unroll
        for (int ntg = 0; ntg < 4; ++ntg)
#pragma unroll
            for (int reg = 0; reg < 4; ++reg)
                eplds[((4 * quad + reg) * 64 + ntg * 16 + col) * 10 + wv] =
                    acc[r][ntg][reg] * scale;
        __syncthreads();
#pragma unroll
        for (int pi = 0; pi < 2; ++pi) {
            const int P = t + pi * 512;       // (b_l, o) pair index
            const int b_l = P >> 6, o = P & 63;
            const float* s = &eplds[P * 10];
            float4 v0, v1;
            v0.x = s[0]; v0.y = s[1]; v0.z = s[2]; v0.w = s[3];
            v1.x = s[4]; v1.y = s[5]; v1.z = s[6]; v1.w = s[7];
            float* op = &out[(size_t)((16 * r + b_l) * 128 + o_base + o) * 1024 + dg * 8];
            *(float4*)op = v0;
            *(float4*)(op + 4) = v1;
        }
    }
}

// ===================== fallback (round-1 kernel, passing) ====================
#define D_TILE 8
#define N_TILE 32
#define KC     16
#define KPAD   40

__global__ __launch_bounds__(256, 2)
void lc1d_fallback(const float* __restrict__ x, const float* __restrict__ w,
                   float* __restrict__ out) {
    __shared__ __align__(16) unsigned short Xs[D_TILE][B_SZ][KPAD];
    __shared__ __align__(16) unsigned short Ws[D_TILE][N_TILE][KPAD];

    const int t     = threadIdx.x;
    const int wv_id = t >> 6;
    const int lane  = t & 63;
    const int col   = lane & 15;
    const int quad  = lane >> 4;

    const int oc_blk = blockIdx.x & 3;
    const int dg     = blockIdx.x >> 2;
    const int o0     = oc_blk * N_TILE;
    const int l0     = dg * (2 * D_TILE);

    f32x4 acc[2][4][2];
#pragma unroll
    for (int dl = 0; dl < 2; ++dl)
#pragma unroll
        for (int mt = 0; mt < 4; ++mt)
#pragma unroll
            for (int nt = 0; nt < 2; ++nt)
                acc[dl][mt][nt] = (f32x4){0.f, 0.f, 0.f, 0.f};

    for (int chunk = 0; chunk < IC_N / KC; ++chunk) {
        const int i0 = chunk * KC;
        float4 xv[16];
#pragma unroll
        for (int r = 0; r < 16; ++r) {
            const int f = t + 256 * r, b = f >> 6, il = (f >> 2) & 15, j = f & 3;
            xv[r] = *(const float4*)&x[(size_t)(b * IC_N + i0 + il) * L_N + l0 + 4 * j];
        }
        float4 wvv[8];
#pragma unroll
        for (int r = 0; r < 8; ++r) {
            const int f = t + 256 * r, ol = f >> 6, il = (f >> 2) & 15, j = f & 3;
            wvv[r] = *(const float4*)&w[(size_t)((o0 + ol) * IC_N + i0 + il) * L_N + l0 + 4 * j];
        }
        __syncthreads();
#pragma unroll
        for (int r = 0; r < 16; ++r) {
            const int f = t + 256 * r, b = f >> 6, il = (f >> 2) & 15, j = f & 3;
            *(unsigned*)&Xs[2 * j][b][2 * il]     = pack2bf(xv[r].x, xv[r].y);
            *(unsigned*)&Xs[2 * j + 1][b][2 * il] = pack2bf(xv[r].z, xv[r].w);
        }
#pragma unroll
        for (int r = 0; r < 8; ++r) {
            const int f = t + 256 * r, ol = f >> 6, il = (f >> 2) & 15, j = f & 3;
            *(unsigned*)&Ws[2 * j][ol][2 * il]     = pack2bf(wvv[r].x, wvv[r].y);
            *(unsigned*)&Ws[2 * j + 1][ol][2 * il] = pack2bf(wvv[r].z, wvv[r].w);
        }
        __syncthreads();
#pragma unroll
        for (int dl = 0; dl < 2; ++dl) {
            const int dp = 2 * wv_id + dl;
            bf16x8 afr[4];
            bf16x8 bfr[2];
#pragma unroll
            for (int mt = 0; mt < 4; ++mt)
                afr[mt] = __builtin_bit_cast(bf16x8, *(const u16x8*)&Xs[dp][16 * mt + col][quad * 8]);
#pragma unroll
            for (int nt = 0; nt < 2; ++nt)
                bfr[nt] = __builtin_bit_cast(bf16x8, *(const u16x8*)&Ws[dp][16 * nt + col][quad * 8]);
#pragma unroll
            for (int mt = 0; mt < 4; ++mt)
#pragma unroll
                for (int nt = 0; nt < 2; ++nt)
                    acc[dl][mt][nt] = __builtin_amdgcn_mfma_f32_16x16x32_bf16(
                        afr[mt], bfr[nt], acc[dl][mt][nt], 0, 0, 0);
        }
    }

    const float scale = 0.088388347648318447f;
    const int dbase = dg * D_TILE + 2 * wv_id;
#pragma unroll
    for (int mt = 0; mt < 4; ++mt)
#pragma unroll
        for (int nt = 0; nt < 2; ++nt)
#pragma unroll
            for (int reg = 0; reg < 4; ++reg) {
                const int b = 16 * mt + 4 * quad + reg;
                const int o = o0 + 16 * nt + col;
                float2 v2;
                v2.x = acc[0][mt][nt][reg] * scale;
                v2.y = acc[1][mt][nt][reg] * scale;
                *(float2*)&out[(size_t)(b * OC_N + o) * OUT_D + dbase] = v2;
            }
}

// ================================ launch ====================================
extern "C" void kernel_launch(void* const* d_in, const int* in_sizes, int n_in,
                              void* d_out, int out_size, void* d_ws, size_t ws_size,
                              hipStream_t stream) {
    const float* x = (const float*)d_in[0];
    const float* w = (const float*)d_in[1];
    float* out     = (float*)d_out;

    const size_t XF_BYTES = (size_t)B_SZ * IC_N * L_N * 2;   // 33,554,432
    const size_t WF_BYTES = (size_t)OC_N * IC_N * L_N * 2;   // 67,108,864

    if (ws_size >= XF_BYTES + WF_BYTES) {
        unsigned short* xf  = (unsigned short*)d_ws;
        unsigned short* wfp = (unsigned short*)((char*)d_ws + XF_BYTES);
        hipLaunchKernelGGL(repack_kernel, dim3(768), dim3(256), 0, stream, x, w, xf, wfp);
        hipLaunchKernelGGL(gemm2_kernel, dim3(256), dim3(512), 0, stream, xf, wfp, out);
    } else {
        hipLaunchKernelGGL(lc1d_fallback, dim3(512), dim3(256), 0, stream, x, w, out);
    }
}